// Round 7
// baseline (299.443 us; speedup 1.0000x reference)
//
#include <hip/hip_runtime.h>

#define DIM_IN 128
#define NREL 4
#define SCAN_CHUNK 1024
#define SRC_MASK 0xFFFFF  // src packed in low 20 bits of csr entry, rel in bits 20+

typedef __attribute__((ext_vector_type(8))) short short8;
typedef __attribute__((ext_vector_type(4))) float floatx4;

__device__ inline unsigned short f2bf(float f) {  // round-to-nearest-even bf16
    union { float f; unsigned int i; } c;
    c.f = f;
    unsigned int r = c.i + 0x7FFF + ((c.i >> 16) & 1);
    return (unsigned short)(r >> 16);
}
__device__ inline float bf2f(unsigned short u) {
    union { unsigned int i; float f; } c;
    c.i = ((unsigned int)u) << 16;
    return c.f;
}

__device__ inline void gload16_lds(const void* g, void* l) {
    __builtin_amdgcn_global_load_lds((const __attribute__((address_space(1))) unsigned int*)g,
                                     (__attribute__((address_space(3))) unsigned int*)l,
                                     16, 0, 0);
}

// ---------------- fused prep: cvt x->bf16, build Wt1[640][128] / Wt2[480][128], count ----------------
__global__ __launch_bounds__(256) void prep_kernel(
    const float* __restrict__ x, unsigned short* __restrict__ xb, int n4,
    const float* __restrict__ Wroot1, const float* __restrict__ Wrel1,
    unsigned short* __restrict__ Wt1,
    const float* __restrict__ Wroot2, const float* __restrict__ Wrel2,
    unsigned short* __restrict__ Wt2,
    const int* __restrict__ ei, const int* __restrict__ et,
    int* __restrict__ counts, int E) {
    int t = blockIdx.x * 256 + threadIdx.x;
    if (t < n4) {
        float4 v = ((const float4*)x)[t];
        ushort4 o;
        o.x = f2bf(v.x); o.y = f2bf(v.y); o.z = f2bf(v.z); o.w = f2bf(v.w);
        ((ushort4*)xb)[t] = o;
    }
    if (t < (640 + 480) * 128) {
        if (t < 640 * 128) {
            int n = t >> 7, k = t & 127;
            float v = (n < 128) ? Wroot1[(size_t)k * 128 + n]
                                : Wrel1[(size_t)((((n - 128) >> 7) * 128) + k) * 128 +
                                        ((n - 128) & 127)];
            Wt1[t] = f2bf(v);
        } else {
            int t2 = t - 640 * 128;
            int n = t2 >> 7, k = t2 & 127;
            float v;
            if (n < 96) {
                v = Wroot2[(size_t)k * 96 + n];
            } else {
                int q = n - 96, r = q / 96, c = q - r * 96;
                v = Wrel2[(size_t)(r * 128 + k) * 96 + c];
            }
            Wt2[t2] = f2bf(v);
        }
    }
    if (t < E) {
        atomicAdd(&counts[(size_t)ei[E + t] * NREL + et[t]], 1);
    }
}

// ---------------- CSR scans / placement ----------------
__device__ int block_exscan256(int v) {
    __shared__ int tmp[256];
    int t = threadIdx.x;
    tmp[t] = v;
    __syncthreads();
    for (int d = 1; d < 256; d <<= 1) {
        int add = (t >= d) ? tmp[t - d] : 0;
        __syncthreads();
        tmp[t] += add;
        __syncthreads();
    }
    return tmp[t] - v;
}

__global__ __launch_bounds__(256) void scanA_kernel(const int* __restrict__ counts,
                                                    int* __restrict__ chunkTot, int nb) {
    int base = blockIdx.x * SCAN_CHUNK + threadIdx.x * 4;
    int s = 0;
#pragma unroll
    for (int i = 0; i < 4; i++) {
        int idx = base + i;
        s += (idx < nb) ? counts[idx] : 0;
    }
    __shared__ int red[256];
    red[threadIdx.x] = s;
    __syncthreads();
    for (int d = 128; d > 0; d >>= 1) {
        if (threadIdx.x < d) red[threadIdx.x] += red[threadIdx.x + d];
        __syncthreads();
    }
    if (threadIdx.x == 0) chunkTot[blockIdx.x] = red[0];
}

__global__ __launch_bounds__(256) void scanB_kernel(const int* __restrict__ chunkTot,
                                                    int* __restrict__ chunkBase, int nChunks,
                                                    int* __restrict__ curM1) {
    int t = threadIdx.x;
    int v = (t < nChunks) ? chunkTot[t] : 0;
    int ex = block_exscan256(v);
    if (t < nChunks) chunkBase[t] = ex;
    if (t == 0) curM1[0] = 0;  // cur[-1] = 0 sentinel (start of bucket 0)
}

__global__ __launch_bounds__(256) void scanC_kernel(const int* __restrict__ counts,
                                                    const int* __restrict__ chunkBase,
                                                    int* __restrict__ cur, int nb) {
    int base = blockIdx.x * SCAN_CHUNK + threadIdx.x * 4;
    int c[4], s = 0;
#pragma unroll
    for (int i = 0; i < 4; i++) {
        int idx = base + i;
        c[i] = (idx < nb) ? counts[idx] : 0;
        s += c[i];
    }
    int pos = block_exscan256(s) + chunkBase[blockIdx.x];
#pragma unroll
    for (int i = 0; i < 4; i++) {
        int idx = base + i;
        if (idx < nb) cur[idx] = pos;  // bucket start; place() advances to bucket end
        pos += c[i];
    }
}

// csr entry = src | (rel<<20). After this kernel cur[g] = end offset of bucket g.
__global__ void place_kernel(const int* __restrict__ ei, const int* __restrict__ et,
                             int* __restrict__ cur, int* __restrict__ csr, int E) {
    int e = blockIdx.x * 256 + threadIdx.x;
    if (e >= E) return;
    int r = et[e];
    int b = ei[E + e] * NREL + r;
    int p = atomicAdd(&cur[b], 1);
    csr[p] = ei[e] | (r << 20);
}

// ---------------- transform GEMM: y[N,NTOT] = A[N,128] @ Wt^T (+bias on chunk 0) ----------------
// grid(x=NTOT/CH chunks, y=ceil(N/128)). BM=128, K=128 single stage (4 panels of [rows][32]).
template <int CH, int NTOT>
__global__ __launch_bounds__(256) void gemm_tf_kernel(
    const unsigned short* __restrict__ A,   // [N,128] bf16
    const unsigned short* __restrict__ Wt,  // [NTOT,128] bf16 (row n = output col n)
    const float* __restrict__ bias,         // root bias, applied for chunk 0 cols
    unsigned short* __restrict__ y,         // [N,NTOT] bf16
    int N) {
    constexpr int NT = CH / 32;            // n-tiles per wave (4 or 3)
    constexpr int BCHP = CH * 4;           // B 16B-chunks per K=32 panel
    __shared__ unsigned short sA[128 * 128];  // 4 panels [128][32]
    __shared__ unsigned short sB[CH * 128];   // 4 panels [CH][32]
    const int t = threadIdx.x;
    const int w = t >> 6;
    const int lane = t & 63;
    const int q = lane >> 4;
    const int l15 = lane & 15;
    const int wm = w >> 1, wn = w & 1;
    const int m0 = blockIdx.y * 128;
    const int c0 = blockIdx.x * CH;

    // stage A: 2048 chunks of 16B (full [128][128] tile)
#pragma unroll
    for (int r = 0; r < 8; r++) {
        int idx = t + r * 256;
        int panel = idx >> 9, rem = idx & 511;
        int row = rem >> 2, ch = rem & 3;
        int rowg = m0 + row;
        if (rowg >= N) rowg = N - 1;
        gload16_lds(A + (size_t)rowg * 128 + panel * 32 + ch * 8, sA + (size_t)idx * 8);
    }
    // stage B: CH*16 chunks (full [CH][128] tile = 4 panels of CH*4 chunks)
#pragma unroll
    for (int r = 0; r < (CH * 16) / 256; r++) {
        int idx = t + r * 256;
        int panel = idx / BCHP, rem = idx - panel * BCHP;
        int nrow = rem >> 2, ch = rem & 3;
        gload16_lds(Wt + (size_t)(c0 + nrow) * 128 + panel * 32 + ch * 8,
                    sB + (size_t)idx * 8);
    }
    __syncthreads();

    floatx4 acc[4][NT];
#pragma unroll
    for (int mt = 0; mt < 4; mt++)
#pragma unroll
        for (int nt = 0; nt < NT; nt++) acc[mt][nt] = (floatx4)0.f;

#pragma unroll
    for (int s = 0; s < 4; s++) {
        short8 aF[4], bF[NT];
#pragma unroll
        for (int mt = 0; mt < 4; mt++)
            aF[mt] = *(const short8*)(sA + s * 4096 + (size_t)(wm * 64 + mt * 16 + l15) * 32 + q * 8);
#pragma unroll
        for (int nt = 0; nt < NT; nt++)
            bF[nt] = *(const short8*)(sB + s * (CH * 32) +
                                      (size_t)(wn * (CH / 2) + nt * 16 + l15) * 32 + q * 8);
#pragma unroll
        for (int mt = 0; mt < 4; mt++)
#pragma unroll
            for (int nt = 0; nt < NT; nt++)
                acc[mt][nt] =
                    __builtin_amdgcn_mfma_f32_16x16x32_bf16(aF[mt], bF[nt], acc[mt][nt], 0, 0, 0);
    }

    // epilogue: C/D layout col=lane&15, row=quad*4+reg. Bias only on chunk 0 (root cols).
#pragma unroll
    for (int nt = 0; nt < NT; nt++) {
        int colc = wn * (CH / 2) + nt * 16 + l15;
        int colg = c0 + colc;
        float bv = (blockIdx.x == 0) ? bias[colc] : 0.f;
#pragma unroll
        for (int mt = 0; mt < 4; mt++) {
            int rbase = m0 + wm * 64 + mt * 16 + q * 4;
#pragma unroll
            for (int r = 0; r < 4; r++) {
                int grow = rbase + r;
                if (grow < N)
                    y[(size_t)grow * NTOT + colg] = f2bf(acc[mt][nt][r] + bv);
            }
        }
    }
}

// ---------------- gather-combine: out[dst] = root + sum_r (1/cnt_r) sum_e y[src][rel slice] ----------------
// One 16-lane group per dst; flat edge list over the dst's 4 contiguous buckets.
// cur[g] = bucket end; bucket start = cur[g-1] (cur[-1]=0 sentinel).
template <int NTOT, int ROOTC, bool RELU_BF16>
__global__ __launch_bounds__(256) void gather_kernel(
    const unsigned short* __restrict__ y, const int* __restrict__ csr,
    const int* __restrict__ cur, void* __restrict__ outp, int N) {
    constexpr int AL = ROOTC / 8;  // active lanes for 8-col-per-lane rows
    const int l = threadIdx.x & 15;
    const int dst = (blockIdx.x * 256 + threadIdx.x) >> 4;
    if (dst >= N) return;
    const int g0 = dst * NREL;
    int o0 = cur[g0 - 1], o1 = cur[g0], o2 = cur[g0 + 1], o3 = cur[g0 + 2], o4 = cur[g0 + 3];
    float sc0 = (o1 > o0) ? 1.f / (float)(o1 - o0) : 0.f;
    float sc1 = (o2 > o1) ? 1.f / (float)(o2 - o1) : 0.f;
    float sc2 = (o3 > o2) ? 1.f / (float)(o3 - o2) : 0.f;
    float sc3 = (o4 > o3) ? 1.f / (float)(o4 - o3) : 0.f;
    int tot = o4 - o0;

    float acc[8];
    if (l < AL) {
        short8 rt = *(const short8*)(y + (size_t)dst * NTOT + l * 8);
#pragma unroll
        for (int c = 0; c < 8; c++) acc[c] = bf2f((unsigned short)rt[c]);
    } else {
#pragma unroll
        for (int c = 0; c < 8; c++) acc[c] = 0.f;
    }

    for (int b0 = 0; b0 < tot; b0 += 16) {
        int m = tot - b0;
        if (m > 16) m = 16;
        int pick = (l < m) ? l : (m - 1);
        int pv = csr[o0 + b0 + pick];  // coalesced index prefetch
        int j = 0;
        for (; j + 1 < m; j += 2) {
            int v0 = __shfl(pv, j, 16);
            int v1 = __shfl(pv, j + 1, 16);
            int s0 = v0 & SRC_MASK, r0 = v0 >> 20;
            int s1 = v1 & SRC_MASK, r1 = v1 >> 20;
            float f0 = (r0 == 0) ? sc0 : (r0 == 1) ? sc1 : (r0 == 2) ? sc2 : sc3;
            float f1 = (r1 == 0) ? sc0 : (r1 == 1) ? sc1 : (r1 == 2) ? sc2 : sc3;
            if (l < AL) {
                short8 u0 = *(const short8*)(y + (size_t)s0 * NTOT + ROOTC + r0 * ROOTC + l * 8);
                short8 u1 = *(const short8*)(y + (size_t)s1 * NTOT + ROOTC + r1 * ROOTC + l * 8);
#pragma unroll
                for (int c = 0; c < 8; c++) acc[c] += f0 * bf2f((unsigned short)u0[c]);
#pragma unroll
                for (int c = 0; c < 8; c++) acc[c] += f1 * bf2f((unsigned short)u1[c]);
            }
        }
        if (j < m) {
            int v0 = __shfl(pv, j, 16);
            int s0 = v0 & SRC_MASK, r0 = v0 >> 20;
            float f0 = (r0 == 0) ? sc0 : (r0 == 1) ? sc1 : (r0 == 2) ? sc2 : sc3;
            if (l < AL) {
                short8 u0 = *(const short8*)(y + (size_t)s0 * NTOT + ROOTC + r0 * ROOTC + l * 8);
#pragma unroll
                for (int c = 0; c < 8; c++) acc[c] += f0 * bf2f((unsigned short)u0[c]);
            }
        }
    }

    if (l < AL) {
        if (RELU_BF16) {
            short8 o;
#pragma unroll
            for (int c = 0; c < 8; c++) o[c] = (short)f2bf(fmaxf(acc[c], 0.f));
            *(short8*)((unsigned short*)outp + (size_t)dst * ROOTC + l * 8) = o;
        } else {
            float4 a = make_float4(acc[0], acc[1], acc[2], acc[3]);
            float4 b = make_float4(acc[4], acc[5], acc[6], acc[7]);
            float4* op = (float4*)((float*)outp + (size_t)dst * ROOTC + l * 8);
            op[0] = a;
            op[1] = b;
        }
    }
}

extern "C" void kernel_launch(void* const* d_in, const int* in_sizes, int n_in,
                              void* d_out, int out_size, void* d_ws, size_t ws_size,
                              hipStream_t stream) {
    const float* x = (const float*)d_in[0];
    const int* ei = (const int*)d_in[1];
    const int* et = (const int*)d_in[2];
    const float* Wroot1 = (const float*)d_in[3];
    const float* Wrel1 = (const float*)d_in[4];
    const float* b1 = (const float*)d_in[5];
    const float* Wroot2 = (const float*)d_in[6];
    const float* Wrel2 = (const float*)d_in[7];
    const float* b2 = (const float*)d_in[8];
    float* out = (float*)d_out;

    int N = in_sizes[0] / DIM_IN;   // 50000 (< 2^20 for csr packing)
    int E = in_sizes[2];
    int nb = N * NREL;
    int nChunks = (nb + SCAN_CHUNK - 1) / SCAN_CHUNK;

    char* p = (char*)d_ws;
    unsigned short* xb = (unsigned short*)p;   p += (size_t)N * 128 * 2;
    unsigned short* hb = (unsigned short*)p;   p += (size_t)N * 128 * 2;
    unsigned short* y1 = (unsigned short*)p;   p += (size_t)N * 640 * 2;
    unsigned short* y2 = (unsigned short*)p;   p += (size_t)N * 480 * 2;
    unsigned short* Wt1 = (unsigned short*)p;  p += (size_t)640 * 128 * 2;
    unsigned short* Wt2 = (unsigned short*)p;  p += (size_t)480 * 128 * 2;
    int* counts = (int*)p;                     p += (size_t)nb * 4;
    int* curBuf = (int*)p;                     p += ((size_t)nb + 1) * 4;
    int* chunkTot = (int*)p;                   p += 256 * 4;
    int* chunkBase = (int*)p;                  p += 256 * 4;
    int* csr = (int*)p;                        p += (size_t)E * 4;
    if ((size_t)(p - (char*)d_ws) > ws_size) return;
    int* cur = curBuf + 1;  // cur[-1] = 0 sentinel

    // ---- CSR build + conversions ----
    int n4 = N * 128 / 4;
    int prepWork = n4;
    if (prepWork < E) prepWork = E;
    if (prepWork < (640 + 480) * 128) prepWork = (640 + 480) * 128;

    hipMemsetAsync(counts, 0, (size_t)nb * sizeof(int), stream);
    prep_kernel<<<(prepWork + 255) / 256, 256, 0, stream>>>(
        x, xb, n4, Wroot1, Wrel1, Wt1, Wroot2, Wrel2, Wt2, ei, et, counts, E);
    scanA_kernel<<<nChunks, 256, 0, stream>>>(counts, chunkTot, nb);
    scanB_kernel<<<1, 256, 0, stream>>>(chunkTot, chunkBase, nChunks, curBuf);
    scanC_kernel<<<nChunks, 256, 0, stream>>>(counts, chunkBase, cur, nb);
    place_kernel<<<(E + 255) / 256, 256, 0, stream>>>(ei, et, cur, csr, E);

    int gM = (N + 127) / 128;
    int gG = (N * 16 + 255) / 256;
    // ---- layer 1: y1 = xb @ [Wroot1|Wrel1] (+b1 on root); hb = relu(combine) ----
    gemm_tf_kernel<128, 640><<<dim3(5, gM), 256, 0, stream>>>(xb, Wt1, b1, y1, N);
    gather_kernel<640, 128, true><<<gG, 256, 0, stream>>>(y1, csr, cur, hb, N);
    // ---- layer 2: y2 = hb @ [Wroot2|Wrel2] (+b2 on root); out = combine (fp32) ----
    gemm_tf_kernel<96, 480><<<dim3(5, gM), 256, 0, stream>>>(hb, Wt2, b2, y2, N);
    gather_kernel<480, 96, false><<<gG, 256, 0, stream>>>(y2, csr, cur, out, N);
}